// Round 23
// baseline (127.519 us; speedup 1.0000x reference)
//
#include <hip/hip_runtime.h>

#define DMODEL 1024
#define NHEADS 16
#define HDIM   64
#define BATCH  2
#define SEQ    2048
#define MROWS  (BATCH*SEQ)

typedef __bf16 bf16x8 __attribute__((ext_vector_type(8)));
typedef __bf16 bf16x4 __attribute__((ext_vector_type(4)));
typedef float floatx4 __attribute__((ext_vector_type(4)));
typedef float floatx16 __attribute__((ext_vector_type(16)));

typedef const __attribute__((address_space(1))) void gvoid;
typedef __attribute__((address_space(3))) void lvoid;

// Q pre-scale: 1/sqrt(64) * log2(e), folded into the QKV GEMM epilogue.
#define QSCALE 0.18033688011112042f

// Cast kernel, 32B-in/16B-out per thread.
__global__ void cast_all(const float* __restrict__ x,
                         const float* __restrict__ wq, const float* __restrict__ wk,
                         const float* __restrict__ wv, const float* __restrict__ wo,
                         __bf16* __restrict__ xb, __bf16* __restrict__ wqb,
                         __bf16* __restrict__ wkb, __bf16* __restrict__ wvb,
                         __bf16* __restrict__ wob)
{
  const int u = blockIdx.x * 256 + threadIdx.x;
  const float* s; __bf16* o; int off;
  if (u < MROWS*DMODEL/8) { s = x; o = xb; off = u; }
  else {
    const int r = u - MROWS*DMODEL/8;
    const int w = r >> 17;
    off = r & 131071;
    s = (w == 0) ? wq : (w == 1) ? wk : (w == 2) ? wv : wo;
    o = (w == 0) ? wqb : (w == 1) ? wkb : (w == 2) ? wvb : wob;
  }
  const float4 f0 = ((const float4*)s)[off*2];
  const float4 f1 = ((const float4*)s)[off*2 + 1];
  bf16x8 v = {(__bf16)f0.x, (__bf16)f0.y, (__bf16)f0.z, (__bf16)f0.w,
              (__bf16)f1.x, (__bf16)f1.y, (__bf16)f1.z, (__bf16)f1.w};
  *(bf16x8*)(o + off*8) = v;
}

// Fused QKV NT GEMM: 128x128 tile, BK=32, double-buffered gload_lds +
// vmcnt(4), XCD-chunk swizzle, grid 768 (3 blocks/CU).
__global__ __launch_bounds__(256, 3)
void gemm_qkv(const unsigned short* __restrict__ A,
              const unsigned short* __restrict__ W0,
              const unsigned short* __restrict__ W1,
              const unsigned short* __restrict__ W2,
              const float* __restrict__ b0,
              const float* __restrict__ b1,
              const float* __restrict__ b2,
              unsigned short* __restrict__ qout,
              unsigned short* __restrict__ kout,
              unsigned short* __restrict__ vout)
{
  const int K = DMODEL;
  __shared__ unsigned short As[2][128*32];
  __shared__ unsigned short Bs[2][128*32];
  const int tid  = threadIdx.x;
  const int wid  = tid >> 6;
  const int lane = tid & 63;

  const int lin = blockIdx.x;
  const int wg  = (lin & 7)*96 + (lin >> 3);
  const int bx  = wg % 24;
  const int by  = wg / 24;
  const int brow = by * 128;
  const int bcol = bx * 128;
  const int wr = (wid >> 1) * 64;
  const int wc = (wid & 1) * 64;

  const int which = bcol >> 10;
  const unsigned short* Bw = which == 0 ? W0 : which == 1 ? W1 : W2;
  const float* bias = which == 0 ? b0 : which == 1 ? b1 : b2;
  const int bcolL = bcol & 1023;

  floatx4 acc[4][4] = {};

  const int sr = wid*16 + (lane >> 2);
  const int sc = (lane & 3) * 8;
  const int fr = lane & 15;
  const int fk = (lane >> 4) * 8;

#define GSTAGE(KT, B) do {                                                     \
    _Pragma("unroll")                                                          \
    for (int i_ = 0; i_ < 2; ++i_) {                                           \
      __builtin_amdgcn_global_load_lds(                                        \
          (gvoid*)(A + (size_t)(brow + i_*64 + sr)*K + (KT) + sc),             \
          (lvoid*)(As[B] + i_*2048 + wid*512), 16, 0, 0);                      \
      __builtin_amdgcn_global_load_lds(                                        \
          (gvoid*)(Bw + (size_t)(bcolL + i_*64 + sr)*K + (KT) + sc),           \
          (lvoid*)(Bs[B] + i_*2048 + wid*512), 16, 0, 0);                      \
    }                                                                          \
  } while (0)

  GSTAGE(0, 0);

  for (int kt = 0; kt < K; kt += 32) {
    const int cur = (kt >> 5) & 1;
    if (kt + 32 < K) {
      GSTAGE(kt + 32, cur ^ 1);
      asm volatile("s_waitcnt vmcnt(4)" ::: "memory");
    } else {
      asm volatile("s_waitcnt vmcnt(0)" ::: "memory");
    }
    __builtin_amdgcn_s_barrier();
    __builtin_amdgcn_sched_barrier(0);

    bf16x8 af[4], bfv[4];
#pragma unroll
    for (int m = 0; m < 4; ++m)
      af[m] = *(const bf16x8*)(As[cur] + (wr + m*16 + fr)*32 + fk);
#pragma unroll
    for (int n = 0; n < 4; ++n)
      bfv[n] = *(const bf16x8*)(Bs[cur] + (wc + n*16 + fr)*32 + fk);
    __builtin_amdgcn_s_setprio(1);
#pragma unroll
    for (int m = 0; m < 4; ++m)
#pragma unroll
      for (int n = 0; n < 4; ++n)
        acc[m][n] = __builtin_amdgcn_mfma_f32_16x16x32_bf16(af[m], bfv[n], acc[m][n], 0, 0, 0);
    __builtin_amdgcn_s_setprio(0);
    __builtin_amdgcn_s_barrier();
  }
#undef GSTAGE

  const int er = (lane >> 4) * 4;
  const int ec = lane & 15;
#pragma unroll
  for (int m = 0; m < 4; ++m) {
#pragma unroll
    for (int n = 0; n < 4; ++n) {
      const int colL = bcolL + wc + n*16 + ec;
      const float bv = bias[colL];
      const int rowb = brow + wr + m*16 + er;
      const int bi = rowb >> 11, s = rowb & 2047;
      const int hh = colL >> 6, dd = colL & 63;
      if (which == 2) {
        bf16x4 v4 = {(__bf16)(acc[m][n][0] + bv), (__bf16)(acc[m][n][1] + bv),
                     (__bf16)(acc[m][n][2] + bv), (__bf16)(acc[m][n][3] + bv)};
        *(bf16x4*)((__bf16*)vout + ((size_t)(bi*NHEADS + hh)*HDIM + dd)*SEQ + s) = v4;
      } else if (which == 0) {
        __bf16* o = (__bf16*)qout;
#pragma unroll
        for (int j = 0; j < 4; ++j)
          o[((size_t)(bi*NHEADS + hh)*SEQ + s + j)*HDIM + dd] =
              (__bf16)((acc[m][n][j] + bv) * QSCALE);
      } else {
        __bf16* o = (__bf16*)kout;
#pragma unroll
        for (int j = 0; j < 4; ++j)
          o[((size_t)(bi*NHEADS + hh)*SEQ + s + j)*HDIM + dd] = (__bf16)(acc[m][n][j] + bv);
      }
    }
  }
}

// Output-projection NT GEMM: 128x64 tile, BK=64, swizzled LDS.
__global__ __launch_bounds__(256, 3)
void gemm_out(const unsigned short* __restrict__ A,
              const unsigned short* __restrict__ W,
              const float* __restrict__ bias,
              float* __restrict__ outf)
{
  const int K = DMODEL;
  __shared__ unsigned short As[2][128*64];
  __shared__ unsigned short Bs[2][64*64];
  const int tid  = threadIdx.x;
  const int wid  = tid >> 6;
  const int lane = tid & 63;

  const int lin = blockIdx.x;
  const int wg  = (lin & 7)*64 + (lin >> 3);
  const int bx  = wg & 15;
  const int by  = wg >> 4;
  const int brow = by * 128;
  const int bcol = bx * 64;
  const int wr = (wid >> 1) * 64;
  const int wc = (wid & 1) * 32;

  floatx4 acc[4][2] = {};

  const int fr  = lane & 15;
  const int hi4 = lane >> 4;

  const int r0 = tid >> 3;
  const int sw = ((tid & 7) ^ (r0 & 7)) * 8;

  auto gstage = [&](int kt, int B) {
#pragma unroll
    for (int i_ = 0; i_ < 4; ++i_)
      __builtin_amdgcn_global_load_lds(
          (gvoid*)(A + (size_t)(brow + i_*32 + r0)*K + kt + sw),
          (lvoid*)(As[B] + (i_*256 + tid)*8), 16, 0, 0);
#pragma unroll
    for (int i_ = 0; i_ < 2; ++i_)
      __builtin_amdgcn_global_load_lds(
          (gvoid*)(W + (size_t)(bcol + i_*32 + r0)*K + kt + sw),
          (lvoid*)(Bs[B] + (i_*256 + tid)*8), 16, 0, 0);
  };

  gstage(0, 0);

  for (int kt = 0; kt < K; kt += 64) {
    const int cur = (kt >> 6) & 1;
    if (kt + 64 < K) {
      gstage(kt + 64, cur ^ 1);
      asm volatile("s_waitcnt vmcnt(6)" ::: "memory");
    } else {
      asm volatile("s_waitcnt vmcnt(0)" ::: "memory");
    }
    __builtin_amdgcn_s_barrier();
    __builtin_amdgcn_sched_barrier(0);

    bf16x8 af[4][2], bfv[2][2];
#pragma unroll
    for (int m = 0; m < 4; ++m) {
      const int ra = wr + m*16 + fr;
#pragma unroll
      for (int c = 0; c < 2; ++c)
        af[m][c] = *(const bf16x8*)(As[cur] + ra*64 + (((c*4 + hi4) ^ (ra & 7)) * 8));
    }
#pragma unroll
    for (int n = 0; n < 2; ++n) {
      const int rb = wc + n*16 + fr;
#pragma unroll
      for (int c = 0; c < 2; ++c)
        bfv[n][c] = *(const bf16x8*)(Bs[cur] + rb*64 + (((c*4 + hi4) ^ (rb & 7)) * 8));
    }
    __builtin_amdgcn_s_setprio(1);
#pragma unroll
    for (int m = 0; m < 4; ++m)
#pragma unroll
      for (int n = 0; n < 2; ++n)
#pragma unroll
        for (int c = 0; c < 2; ++c)
          acc[m][n] = __builtin_amdgcn_mfma_f32_16x16x32_bf16(af[m][c], bfv[n][c], acc[m][n], 0, 0, 0);
    __builtin_amdgcn_s_setprio(0);
    __builtin_amdgcn_s_barrier();
  }

  const int er = hi4 * 4;
  const int ec = lane & 15;
#pragma unroll
  for (int m = 0; m < 4; ++m) {
#pragma unroll
    for (int n = 0; n < 2; ++n) {
      const int col = bcol + wc + n*16 + ec;
      const float bv = bias[col];
      const int rowb = brow + wr + m*16 + er;
#pragma unroll
      for (int j = 0; j < 4; ++j)
        outf[(size_t)(rowb + j)*DMODEL + col] = acc[m][n][j] + bv;
    }
  }
}

// Flash attention, 32x32 MFMA (LDS-op relief: same 16B/lane operands feed 2x
// the MACs). Wave = 32 q-rows, QBLK=128; 2-way key-split (4 row-waves each).
// LDS plan (exactly 80 KiB -> 2 blocks/CU): Ks single-buffered 16 KiB (K is
// dead after QK^T; K(t+1) staged right after the post-QK^T barrier, drained
// by next step's vmcnt+barrier), Vs double-buffered 32 KiB, DEDICATED Ps
// 32 KiB (the r22 bug was P overflowing an 8 KiB K buffer). 2 barriers/step.
// Grid 512; pair (c, c+256) -> qt j / 15-j -> 17 uniform steps per CU slot.
// Frag layouts (m74/m101): A/B row=l&31, k=(l>>5)*8; C/D col=l&31,
// row=(r&3)+8*(r>>2)+4*(l>>5). Fixed-shift softmax, Q pre-scaled.
__global__ __launch_bounds__(512, 4)
void attn_fwd(const unsigned short* __restrict__ qb,
              const unsigned short* __restrict__ kb,
              const unsigned short* __restrict__ vtb,
              const int* __restrict__ ids,
              unsigned short* __restrict__ outb)
{
  const int bx = blockIdx.x;
  const int hb = bx & 31;
  const int j  = (bx >> 5) & 7;
  const int qt = (bx >> 8) ? 15 - j : j;
  const int h = hb & 15, bi = hb >> 4;

  const int tid = threadIdx.x, wid = tid >> 6, lane = tid & 63;
  const int grp  = wid >> 2;                // key-half group
  const int wid4 = wid & 3;                 // row-wave (32 q-rows)
  const size_t hoff = (size_t)(bi*NHEADS + h) * SEQ * HDIM;
  const unsigned short* Qh  = qb  + hoff;
  const unsigned short* Kh  = kb  + hoff;
  const unsigned short* Vth = vtb + hoff;   // [d][s]

  __shared__ unsigned short Ks[2][64*64];     // [grp] single-buffer, 16 KiB
  __shared__ unsigned short Vs[2][2][64*64];  // [grp][buf], 32 KiB
  __shared__ unsigned short Ps[8][32*64];     // per-wave P, 32 KiB -> 80 KiB
  float* LOf = (float*)Ps;                    // merge overlay: 128x64 f32
  float* Ll  = (float*)Ks;                    // merge overlay: 128 f32

  const int q32 = lane & 31;
  const int hi2 = lane >> 5;
  const int qbase = qt * 128;
  const int rowb = qbase + wid4*32;

  const int gt = tid & 255;
  const int r0 = gt >> 3;
  const int sw = ((gt & 7) ^ (r0 & 7)) * 8;
  unsigned short* Pw = Ps[wid];

#define STAGEK(T) do {                                                         \
    const unsigned short* kbase_ = Kh + (size_t)((T)*64) * HDIM;               \
    __builtin_amdgcn_global_load_lds((gvoid*)(kbase_ + r0*64 + sw),            \
                                     (lvoid*)(Ks[grp] + gt*8), 16, 0, 0);      \
    __builtin_amdgcn_global_load_lds((gvoid*)(kbase_ + (r0+32)*64 + sw),       \
                                     (lvoid*)(Ks[grp] + (gt+256)*8), 16, 0, 0);\
  } while (0)
#define STAGEV(T, B) do {                                                      \
    const unsigned short* vbase_ = Vth + (T)*64;                               \
    __builtin_amdgcn_global_load_lds((gvoid*)(vbase_ + (size_t)r0*SEQ + sw),   \
                                     (lvoid*)(Vs[grp][B] + gt*8), 16, 0, 0);   \
    __builtin_amdgcn_global_load_lds((gvoid*)(vbase_ + (size_t)(r0+32)*SEQ + sw),\
                                     (lvoid*)(Vs[grp][B] + (gt+256)*8), 16, 0, 0);\
  } while (0)

  // Q B-fragments: col=q32, d = s*16 + hi2*8 + j
  bf16x8 qf[4];
#pragma unroll
  for (int s = 0; s < 4; ++s)
    qf[s] = *(const bf16x8*)(Qh + (size_t)(rowb + q32)*HDIM + s*16 + hi2*8);

  float lsum = 0.f;
  floatx16 OA = {};
  floatx16 OB = {};

  const int cnt = qt + 1;                   // per group (nT = 2qt+2, even)
  const int tb  = grp * cnt;

  STAGEK(tb);
  STAGEV(tb, 0);

  for (int i = 0; i < cnt; ++i) {
    const int t = tb + i;
    const int kb0 = t * 64;
    const int pv = ids[bi*SEQ + kb0 + lane];
    asm volatile("s_waitcnt vmcnt(0)" ::: "memory");
    const unsigned long long wm = __ballot(pv == 0);
    __builtin_amdgcn_s_barrier();             // K(t), V(t) ready everywhere
    __builtin_amdgcn_sched_barrier(0);

    const int vbuf = i & 1;
    const bool dead_all = (kb0 >= rowb + 32);
    const bool masked = (kb0 + 63 > rowb) || (wm != 0ull);

    if (!dead_all) {
      // QK^T per 32-key subtile; exp + P-store immediately (dedicated Ps)
#pragma unroll
      for (int kt2 = 0; kt2 < 2; ++kt2) {
        floatx16 st = {};
        const int krow = kt2*32 + q32;
        __builtin_amdgcn_s_setprio(1);
#pragma unroll
        for (int s = 0; s < 4; ++s) {
          bf16x8 kf = *(const bf16x8*)(Ks[grp] + krow*64 +
                                       (((s*2 + hi2) ^ (krow & 7)) * 8));
          st = __builtin_amdgcn_mfma_f32_32x32x16_bf16(kf, qf[s], st, 0, 0, 0);
        }
        __builtin_amdgcn_s_setprio(0);

        float p[16];
        if (!masked) {
#pragma unroll
          for (int r = 0; r < 16; ++r) { p[r] = exp2f(st[r]); lsum += p[r]; }
        } else {
          const int qg = rowb + q32;
#pragma unroll
          for (int r = 0; r < 16; ++r) {
            const int crow = (r & 3) + 4*hi2 + 8*(r >> 2);
            const int kl = kt2*32 + crow;
            const bool dead = ((kb0 + kl) > qg) || (((wm >> kl) & 1ull) != 0ull);
            p[r] = dead ? 0.f : exp2f(st[r]);
            lsum += p[r];
          }
        }
#pragma unroll
        for (int g = 0; g < 4; ++g) {
          bf16x4 pk = {(__bf16)p[g*4], (__bf16)p[g*4+1],
                       (__bf16)p[g*4+2], (__bf16)p[g*4+3]};
          const int c = kt2*4 + g;
          *(bf16x4*)(Pw + q32*64 + ((c ^ (q32 & 7)) * 8) + hi2*4) = pk;
        }
      }
    }
    __builtin_amdgcn_s_barrier();             // all K reads done block-wide

    if (i + 1 < cnt) {
      STAGEK(t + 1);                          // K buffer free (K dead)
      STAGEV(t + 1, vbuf ^ 1);
    }

    if (!dead_all) {
      __builtin_amdgcn_s_setprio(1);
#pragma unroll
      for (int ks = 0; ks < 4; ++ks) {
        const int ch = ((ks*2 + hi2) ^ (q32 & 7)) * 8;
        bf16x8 pf  = *(const bf16x8*)(Pw + q32*64 + ch);
        bf16x8 vf0 = *(const bf16x8*)(Vs[grp][vbuf] + q32*64 + ch);
        bf16x8 vf1 = *(const bf16x8*)(Vs[grp][vbuf] + (32 + q32)*64 + ch);
        OA = __builtin_amdgcn_mfma_f32_32x32x16_bf16(pf, vf0, OA, 0, 0, 0);
        OB = __builtin_amdgcn_mfma_f32_32x32x16_bf16(pf, vf1, OB, 0, 0, 0);
      }
      __builtin_amdgcn_s_setprio(0);
    }
  }
#undef STAGEK
#undef STAGEV

  // fold hi2 halves: lane now has total l for q-row q32 (this key half)
  float lt = lsum + __shfl_xor(lsum, 32);

  __syncthreads();                            // all PV done; Ps/Ks now dead

  // merge: group1 -> LDS overlays, group0 adds + normalizes + writes
  if (grp == 1) {
#pragma unroll
    for (int r = 0; r < 16; ++r) {
      const int crow = (r & 3) + 4*hi2 + 8*(r >> 2);
      const int row = wid4*32 + crow;
      LOf[row*64 + q32]      = OA[r];
      LOf[row*64 + 32 + q32] = OB[r];
    }
    if (hi2 == 0) Ll[wid4*32 + q32] = lt;
  }
  __syncthreads();
  if (grp == 0) {
#pragma unroll
    for (int r = 0; r < 16; ++r) {
      const int crow = (r & 3) + 4*hi2 + 8*(r >> 2);
      const int rloc = wid4*32 + crow;
      const float inv = 1.f / (__shfl(lt, crow) + Ll[rloc]);
      const size_t row = (size_t)(bi*SEQ + qbase + rloc);
      const float o0 = OA[r] + LOf[rloc*64 + q32];
      const float o1 = OB[r] + LOf[rloc*64 + 32 + q32];
      ((__bf16*)outb)[row*DMODEL + h*HDIM + q32]      = (__bf16)(o0 * inv);
      ((__bf16*)outb)[row*DMODEL + h*HDIM + 32 + q32] = (__bf16)(o1 * inv);
    }
  }
}

extern "C" void kernel_launch(void* const* d_in, const int* in_sizes, int n_in,
                              void* d_out, int out_size, void* d_ws, size_t ws_size,
                              hipStream_t stream)
{
  const float* x  = (const float*)d_in[0];
  const int*   ids= (const int*)d_in[1];
  const float* Wq = (const float*)d_in[2];
  const float* bq = (const float*)d_in[3];
  const float* Wk = (const float*)d_in[4];
  const float* bk = (const float*)d_in[5];
  const float* Wv = (const float*)d_in[6];
  const float* bv = (const float*)d_in[7];
  const float* Wo = (const float*)d_in[8];
  const float* bo = (const float*)d_in[9];
  float* out = (float*)d_out;

  char* ws = (char*)d_ws;
  unsigned short* xb   = (unsigned short*)(ws);
  unsigned short* wqb  = (unsigned short*)(ws + ( 8u<<20));
  unsigned short* wkb  = (unsigned short*)(ws + (10u<<20));
  unsigned short* wvb  = (unsigned short*)(ws + (12u<<20));
  unsigned short* wob  = (unsigned short*)(ws + (14u<<20));
  unsigned short* qbuf = (unsigned short*)(ws + (16u<<20));
  unsigned short* kbuf = (unsigned short*)(ws + (24u<<20));
  unsigned short* vbuf = (unsigned short*)(ws + (32u<<20));  // [b,h,d,s]
  unsigned short* abuf = (unsigned short*)(ws + (40u<<20));

  cast_all<<<4096, 256, 0, stream>>>(x, Wq, Wk, Wv, Wo,
                                     (__bf16*)xb, (__bf16*)wqb, (__bf16*)wkb,
                                     (__bf16*)wvb, (__bf16*)wob);

  gemm_qkv<<<768, 256, 0, stream>>>(xb, wqb, wkb, wvb, bq, bk, bv,
                                    qbuf, kbuf, vbuf);

  attn_fwd<<<512, 512, 0, stream>>>(qbuf, kbuf, vbuf, ids, abuf);

  gemm_out<<<512, 256, 0, stream>>>(abuf, wob, bo, out);
}

// Round 24
// 105.118 us; speedup vs baseline: 1.2131x; 1.2131x over previous
//
#include <hip/hip_runtime.h>

#define DMODEL 1024
#define NHEADS 16
#define HDIM   64
#define BATCH  2
#define SEQ    2048
#define MROWS  (BATCH*SEQ)

typedef __bf16 bf16x8 __attribute__((ext_vector_type(8)));
typedef __bf16 bf16x4 __attribute__((ext_vector_type(4)));
typedef float floatx4 __attribute__((ext_vector_type(4)));

typedef const __attribute__((address_space(1))) void gvoid;
typedef __attribute__((address_space(3))) void lvoid;

template<bool V> struct ICb { static constexpr bool value = V; };

// Q pre-scale: 1/sqrt(64) * log2(e), folded into the QKV GEMM epilogue.
#define QSCALE 0.18033688011112042f

// Cast kernel, 32B-in/16B-out per thread: x (524288 units) then 4x W (131072).
__global__ void cast_all(const float* __restrict__ x,
                         const float* __restrict__ wq, const float* __restrict__ wk,
                         const float* __restrict__ wv, const float* __restrict__ wo,
                         __bf16* __restrict__ xb, __bf16* __restrict__ wqb,
                         __bf16* __restrict__ wkb, __bf16* __restrict__ wvb,
                         __bf16* __restrict__ wob)
{
  const int u = blockIdx.x * 256 + threadIdx.x;
  const float* s; __bf16* o; int off;
  if (u < MROWS*DMODEL/8) { s = x; o = xb; off = u; }
  else {
    const int r = u - MROWS*DMODEL/8;
    const int w = r >> 17;
    off = r & 131071;
    s = (w == 0) ? wq : (w == 1) ? wk : (w == 2) ? wv : wo;
    o = (w == 0) ? wqb : (w == 1) ? wkb : (w == 2) ? wvb : wob;
  }
  const float4 f0 = ((const float4*)s)[off*2];
  const float4 f1 = ((const float4*)s)[off*2 + 1];
  bf16x8 v = {(__bf16)f0.x, (__bf16)f0.y, (__bf16)f0.z, (__bf16)f0.w,
              (__bf16)f1.x, (__bf16)f1.y, (__bf16)f1.z, (__bf16)f1.w};
  *(bf16x8*)(o + off*8) = v;
}

// Fused QKV NT GEMM: 128x128 tile, BK=32, double-buffered gload_lds +
// vmcnt(4), XCD-chunk swizzle, grid 768 (3 blocks/CU).
__global__ __launch_bounds__(256, 3)
void gemm_qkv(const unsigned short* __restrict__ A,
              const unsigned short* __restrict__ W0,
              const unsigned short* __restrict__ W1,
              const unsigned short* __restrict__ W2,
              const float* __restrict__ b0,
              const float* __restrict__ b1,
              const float* __restrict__ b2,
              unsigned short* __restrict__ qout,
              unsigned short* __restrict__ kout,
              unsigned short* __restrict__ vout)
{
  const int K = DMODEL;
  __shared__ unsigned short As[2][128*32];
  __shared__ unsigned short Bs[2][128*32];
  const int tid  = threadIdx.x;
  const int wid  = tid >> 6;
  const int lane = tid & 63;

  const int lin = blockIdx.x;
  const int wg  = (lin & 7)*96 + (lin >> 3);
  const int bx  = wg % 24;
  const int by  = wg / 24;
  const int brow = by * 128;
  const int bcol = bx * 128;
  const int wr = (wid >> 1) * 64;
  const int wc = (wid & 1) * 64;

  const int which = bcol >> 10;
  const unsigned short* Bw = which == 0 ? W0 : which == 1 ? W1 : W2;
  const float* bias = which == 0 ? b0 : which == 1 ? b1 : b2;
  const int bcolL = bcol & 1023;

  floatx4 acc[4][4] = {};

  const int sr = wid*16 + (lane >> 2);
  const int sc = (lane & 3) * 8;
  const int fr = lane & 15;
  const int fk = (lane >> 4) * 8;

#define GSTAGE(KT, B) do {                                                     \
    _Pragma("unroll")                                                          \
    for (int i_ = 0; i_ < 2; ++i_) {                                           \
      __builtin_amdgcn_global_load_lds(                                        \
          (gvoid*)(A + (size_t)(brow + i_*64 + sr)*K + (KT) + sc),             \
          (lvoid*)(As[B] + i_*2048 + wid*512), 16, 0, 0);                      \
      __builtin_amdgcn_global_load_lds(                                        \
          (gvoid*)(Bw + (size_t)(bcolL + i_*64 + sr)*K + (KT) + sc),           \
          (lvoid*)(Bs[B] + i_*2048 + wid*512), 16, 0, 0);                      \
    }                                                                          \
  } while (0)

  GSTAGE(0, 0);

  for (int kt = 0; kt < K; kt += 32) {
    const int cur = (kt >> 5) & 1;
    if (kt + 32 < K) {
      GSTAGE(kt + 32, cur ^ 1);
      asm volatile("s_waitcnt vmcnt(4)" ::: "memory");
    } else {
      asm volatile("s_waitcnt vmcnt(0)" ::: "memory");
    }
    __builtin_amdgcn_s_barrier();
    __builtin_amdgcn_sched_barrier(0);

    bf16x8 af[4], bfv[4];
#pragma unroll
    for (int m = 0; m < 4; ++m)
      af[m] = *(const bf16x8*)(As[cur] + (wr + m*16 + fr)*32 + fk);
#pragma unroll
    for (int n = 0; n < 4; ++n)
      bfv[n] = *(const bf16x8*)(Bs[cur] + (wc + n*16 + fr)*32 + fk);
    __builtin_amdgcn_s_setprio(1);
#pragma unroll
    for (int m = 0; m < 4; ++m)
#pragma unroll
      for (int n = 0; n < 4; ++n)
        acc[m][n] = __builtin_amdgcn_mfma_f32_16x16x32_bf16(af[m], bfv[n], acc[m][n], 0, 0, 0);
    __builtin_amdgcn_s_setprio(0);
    __builtin_amdgcn_s_barrier();
  }
#undef GSTAGE

  const int er = (lane >> 4) * 4;
  const int ec = lane & 15;
#pragma unroll
  for (int m = 0; m < 4; ++m) {
#pragma unroll
    for (int n = 0; n < 4; ++n) {
      const int colL = bcolL + wc + n*16 + ec;
      const float bv = bias[colL];
      const int rowb = brow + wr + m*16 + er;
      const int bi = rowb >> 11, s = rowb & 2047;
      const int hh = colL >> 6, dd = colL & 63;
      if (which == 2) {
        bf16x4 v4 = {(__bf16)(acc[m][n][0] + bv), (__bf16)(acc[m][n][1] + bv),
                     (__bf16)(acc[m][n][2] + bv), (__bf16)(acc[m][n][3] + bv)};
        *(bf16x4*)((__bf16*)vout + ((size_t)(bi*NHEADS + hh)*HDIM + dd)*SEQ + s) = v4;
      } else if (which == 0) {
        __bf16* o = (__bf16*)qout;
#pragma unroll
        for (int j = 0; j < 4; ++j)
          o[((size_t)(bi*NHEADS + hh)*SEQ + s + j)*HDIM + dd] =
              (__bf16)((acc[m][n][j] + bv) * QSCALE);
      } else {
        __bf16* o = (__bf16*)kout;
#pragma unroll
        for (int j = 0; j < 4; ++j)
          o[((size_t)(bi*NHEADS + hh)*SEQ + s + j)*HDIM + dd] = (__bf16)(acc[m][n][j] + bv);
      }
    }
  }
}

// Output-projection NT GEMM: 128x64 tile, BK=64, swizzled LDS.
__global__ __launch_bounds__(256, 3)
void gemm_out(const unsigned short* __restrict__ A,
              const unsigned short* __restrict__ W,
              const float* __restrict__ bias,
              float* __restrict__ outf)
{
  const int K = DMODEL;
  __shared__ unsigned short As[2][128*64];
  __shared__ unsigned short Bs[2][64*64];
  const int tid  = threadIdx.x;
  const int wid  = tid >> 6;
  const int lane = tid & 63;

  const int lin = blockIdx.x;
  const int wg  = (lin & 7)*64 + (lin >> 3);
  const int bx  = wg & 15;
  const int by  = wg >> 4;
  const int brow = by * 128;
  const int bcol = bx * 64;
  const int wr = (wid >> 1) * 64;
  const int wc = (wid & 1) * 32;

  floatx4 acc[4][2] = {};

  const int fr  = lane & 15;
  const int hi4 = lane >> 4;

  const int r0 = tid >> 3;
  const int sw = ((tid & 7) ^ (r0 & 7)) * 8;

  auto gstage = [&](int kt, int B) {
#pragma unroll
    for (int i_ = 0; i_ < 4; ++i_)
      __builtin_amdgcn_global_load_lds(
          (gvoid*)(A + (size_t)(brow + i_*32 + r0)*K + kt + sw),
          (lvoid*)(As[B] + (i_*256 + tid)*8), 16, 0, 0);
#pragma unroll
    for (int i_ = 0; i_ < 2; ++i_)
      __builtin_amdgcn_global_load_lds(
          (gvoid*)(W + (size_t)(bcol + i_*32 + r0)*K + kt + sw),
          (lvoid*)(Bs[B] + (i_*256 + tid)*8), 16, 0, 0);
  };

  gstage(0, 0);

  for (int kt = 0; kt < K; kt += 64) {
    const int cur = (kt >> 6) & 1;
    if (kt + 64 < K) {
      gstage(kt + 64, cur ^ 1);
      asm volatile("s_waitcnt vmcnt(6)" ::: "memory");
    } else {
      asm volatile("s_waitcnt vmcnt(0)" ::: "memory");
    }
    __builtin_amdgcn_s_barrier();
    __builtin_amdgcn_sched_barrier(0);

    bf16x8 af[4][2], bfv[2][2];
#pragma unroll
    for (int m = 0; m < 4; ++m) {
      const int ra = wr + m*16 + fr;
#pragma unroll
      for (int c = 0; c < 2; ++c)
        af[m][c] = *(const bf16x8*)(As[cur] + ra*64 + (((c*4 + hi4) ^ (ra & 7)) * 8));
    }
#pragma unroll
    for (int n = 0; n < 2; ++n) {
      const int rb = wc + n*16 + fr;
#pragma unroll
      for (int c = 0; c < 2; ++c)
        bfv[n][c] = *(const bf16x8*)(Bs[cur] + rb*64 + (((c*4 + hi4) ^ (rb & 7)) * 8));
    }
    __builtin_amdgcn_s_setprio(1);
#pragma unroll
    for (int m = 0; m < 4; ++m)
#pragma unroll
      for (int n = 0; n < 2; ++n)
#pragma unroll
        for (int c = 0; c < 2; ++c)
          acc[m][n] = __builtin_amdgcn_mfma_f32_16x16x32_bf16(af[m][c], bfv[n][c], acc[m][n], 0, 0, 0);
    __builtin_amdgcn_s_setprio(0);
    __builtin_amdgcn_s_barrier();
  }

  const int er = hi4 * 4;
  const int ec = lane & 15;
#pragma unroll
  for (int m = 0; m < 4; ++m) {
#pragma unroll
    for (int n = 0; n < 2; ++n) {
      const int col = bcol + wc + n*16 + ec;
      const float bv = bias[col];
      const int rowb = brow + wr + m*16 + er;
#pragma unroll
      for (int j = 0; j < 4; ++j)
        outf[(size_t)(rowb + j)*DMODEL + col] = acc[m][n][j] + bv;
    }
  }
}

// Flash attention, fixed-shift softmax, KEY-SPLIT + PAIRED form (best: ~52us).
// 8-wave blocks; waves 0-3 / 4-7 split the key range of the SAME 64 q-rows,
// double-buffered K/V via global_load_lds + vmcnt(4). Blocks process q-tiles
// (pr, 31-pr) -> every block exactly 17 group-steps; grid (32,16) = 512 =
// exactly 2/CU (80 KiB LDS), uniform. Fixed-shift merge via LDS.
__global__ __launch_bounds__(512, 4)
void attn_fwd(const unsigned short* __restrict__ qb,
              const unsigned short* __restrict__ kb,
              const unsigned short* __restrict__ vtb,
              const int* __restrict__ ids,
              unsigned short* __restrict__ outb)
{
  const int hb = blockIdx.x;
  const int pr = blockIdx.y;
  const int h = hb & 15, bi = hb >> 4;

  const int tid = threadIdx.x, wid = tid >> 6, lane = tid & 63;
  const int grp  = wid >> 2;
  const int wid4 = wid & 3;
  const size_t hoff = (size_t)(bi*NHEADS + h) * SEQ * HDIM;
  const unsigned short* Qh  = qb  + hoff;
  const unsigned short* Kh  = kb  + hoff;
  const unsigned short* Vth = vtb + hoff;   // [d][s]

  __shared__ unsigned short Ks[2][2][64*64];
  __shared__ unsigned short Vs[2][2][64*64];
  __shared__ unsigned short Ps[8][16*64];
  float* LOf = (float*)Ps;
  float* Ll  = (float*)Ks;

  const int q_   = lane & 15;
  const int hi4  = lane >> 4;
  const int koff = hi4 * 4;

  const int gt = tid & 255;
  const int r0 = gt >> 3;
  const int sw = ((gt & 7) ^ (r0 & 7)) * 8;
  unsigned short* Pw = Ps[wid];

#define STAGE(T, B) do {                                                       \
    const unsigned short* kbase_ = Kh + (size_t)((T)*64) * HDIM;               \
    const unsigned short* vbase_ = Vth + (T)*64;                               \
    __builtin_amdgcn_global_load_lds((gvoid*)(kbase_ + r0*64 + sw),            \
                                     (lvoid*)(Ks[grp][B] + gt*8), 16, 0, 0);   \
    __builtin_amdgcn_global_load_lds((gvoid*)(kbase_ + (r0+32)*64 + sw),       \
                                     (lvoid*)(Ks[grp][B] + (gt+256)*8), 16, 0, 0);\
    __builtin_amdgcn_global_load_lds((gvoid*)(vbase_ + (size_t)r0*SEQ + sw),   \
                                     (lvoid*)(Vs[grp][B] + gt*8), 16, 0, 0);   \
    __builtin_amdgcn_global_load_lds((gvoid*)(vbase_ + (size_t)(r0+32)*SEQ + sw),\
                                     (lvoid*)(Vs[grp][B] + (gt+256)*8), 16, 0, 0);\
  } while (0)

  for (int half = 0; half < 2; ++half) {
    const int qt = half ? 31 - pr : pr;
    const int qbase = qt * 64;
    const int qg = qbase + wid4*16 + q_;

    bf16x8 qf[2];
#pragma unroll
    for (int c = 0; c < 2; ++c)
      qf[c] = *(const bf16x8*)(Qh + (size_t)qg*HDIM + c*32 + hi4*8);

    float lsum = 0.f;
    floatx4 Oacc[4] = {};

    auto step = [&](auto Mc, int kb0, int bufc, unsigned long long wm) {
      constexpr bool MASKED = decltype(Mc)::value;

      floatx4 st[4];
      __builtin_amdgcn_s_setprio(1);
#pragma unroll
      for (int t = 0; t < 4; ++t) {
        st[t] = (floatx4){0.f, 0.f, 0.f, 0.f};
        const int kr = t*16 + q_;
#pragma unroll
        for (int c = 0; c < 2; ++c) {
          const int cd = ((c*4 + hi4) ^ (kr & 7)) * 8;
          bf16x8 kf = *(const bf16x8*)(Ks[grp][bufc] + kr*64 + cd);
          st[t] = __builtin_amdgcn_mfma_f32_16x16x32_bf16(kf, qf[c], st[t], 0, 0, 0);
        }
      }
      __builtin_amdgcn_s_setprio(0);

      float ps = 0.f;
#pragma unroll
      for (int t = 0; t < 4; ++t) {
        float p[4];
#pragma unroll
        for (int r = 0; r < 4; ++r) {
          float pv = exp2f(st[t][r]);               // Q pre-scaled
          if (MASKED) {
            const int ko = t*16 + koff + r;
            const bool dead = ((kb0 + ko) > qg) || (((wm >> ko) & 1ull) != 0ull);
            pv = dead ? 0.f : pv;
          }
          p[r] = pv;
          ps += pv;
        }
        bf16x4 pk = {(__bf16)p[0], (__bf16)p[1], (__bf16)p[2], (__bf16)p[3]};
        const int ko = t*16 + koff;
        *(bf16x4*)(Pw + q_*64 + (((ko >> 3) ^ (q_ & 7)) * 8) + (ko & 7)) = pk;
      }
      lsum += ps;

      __builtin_amdgcn_s_setprio(1);
#pragma unroll
      for (int cp = 0; cp < 2; ++cp) {
        const int ko = cp*32 + hi4*8;
        bf16x8 pf = *(const bf16x8*)(Pw + q_*64 + (((ko >> 3) ^ (q_ & 7)) * 8));
#pragma unroll
        for (int n = 0; n < 4; ++n) {
          const int d = n*16 + q_;
          const int cd = ((cp*4 + hi4) ^ (d & 7)) * 8;
          bf16x8 vf = *(const bf16x8*)(Vs[grp][bufc] + d*64 + cd);
          Oacc[n] = __builtin_amdgcn_mfma_f32_16x16x32_bf16(pf, vf, Oacc[n], 0, 0, 0);
        }
      }
      __builtin_amdgcn_s_setprio(0);
    };

    const int nT = qt + 1;
    const int h0 = (nT + 1) >> 1;
    const int cnt = (grp == 0) ? h0 : nT - h0;
    const int tb  = (grp == 0) ? 0 : h0;

    if (cnt > 0) STAGE(tb, 0);

    for (int i = 0; i < h0; ++i) {
      const bool valid = (i < cnt);
      const int t = tb + i;
      const int kb0 = t * 64;
      int pv = 1;
      if (valid) pv = ids[bi*SEQ + kb0 + lane];
      if (i + 1 < cnt) {
        STAGE(t + 1, (i + 1) & 1);
        asm volatile("s_waitcnt vmcnt(4)" ::: "memory");
      } else {
        asm volatile("s_waitcnt vmcnt(0)" ::: "memory");
      }
      const unsigned long long wm = __ballot(pv == 0);
      __builtin_amdgcn_s_barrier();
      __builtin_amdgcn_sched_barrier(0);

      if (valid) {
        const int bufc = i & 1;
        if ((t != nT - 1) && wm == 0ull) step(ICb<false>{}, kb0, bufc, 0ull);
        else                             step(ICb<true >{}, kb0, bufc, wm);
      }
      __builtin_amdgcn_s_barrier();
    }

    float lt = lsum + __shfl_xor(lsum, 16);
    lt += __shfl_xor(lt, 32);

    if (grp == 1) {
#pragma unroll
      for (int r = 0; r < 4; ++r)
#pragma unroll
        for (int n = 0; n < 4; ++n)
          LOf[(wid4*16 + koff + r)*64 + n*16 + q_] = Oacc[n][r];
      if (hi4 == 0) Ll[wid4*16 + q_] = lt;
    }
    __syncthreads();
    if (grp == 0) {
#pragma unroll
      for (int r = 0; r < 4; ++r) {
        const int rloc = wid4*16 + koff + r;
        const float inv = 1.f / (__shfl(lt, koff + r) + Ll[rloc]);
        const int row = bi*SEQ + qbase + rloc;
#pragma unroll
        for (int n = 0; n < 4; ++n) {
          const float o = Oacc[n][r] + LOf[rloc*64 + n*16 + q_];
          ((__bf16*)outb)[(size_t)row*DMODEL + h*HDIM + n*16 + q_] = (__bf16)(o * inv);
        }
      }
    }
    __syncthreads();
  }
#undef STAGE
}

extern "C" void kernel_launch(void* const* d_in, const int* in_sizes, int n_in,
                              void* d_out, int out_size, void* d_ws, size_t ws_size,
                              hipStream_t stream)
{
  const float* x  = (const float*)d_in[0];
  const int*   ids= (const int*)d_in[1];
  const float* Wq = (const float*)d_in[2];
  const float* bq = (const float*)d_in[3];
  const float* Wk = (const float*)d_in[4];
  const float* bk = (const float*)d_in[5];
  const float* Wv = (const float*)d_in[6];
  const float* bv = (const float*)d_in[7];
  const float* Wo = (const float*)d_in[8];
  const float* bo = (const float*)d_in[9];
  float* out = (float*)d_out;

  char* ws = (char*)d_ws;
  unsigned short* xb   = (unsigned short*)(ws);
  unsigned short* wqb  = (unsigned short*)(ws + ( 8u<<20));
  unsigned short* wkb  = (unsigned short*)(ws + (10u<<20));
  unsigned short* wvb  = (unsigned short*)(ws + (12u<<20));
  unsigned short* wob  = (unsigned short*)(ws + (14u<<20));
  unsigned short* qbuf = (unsigned short*)(ws + (16u<<20));
  unsigned short* kbuf = (unsigned short*)(ws + (24u<<20));
  unsigned short* vbuf = (unsigned short*)(ws + (32u<<20));  // [b,h,d,s]
  unsigned short* abuf = (unsigned short*)(ws + (40u<<20));

  cast_all<<<4096, 256, 0, stream>>>(x, Wq, Wk, Wv, Wo,
                                     (__bf16*)xb, (__bf16*)wqb, (__bf16*)wkb,
                                     (__bf16*)wvb, (__bf16*)wob);

  gemm_qkv<<<768, 256, 0, stream>>>(xb, wqb, wkb, wvb, bq, bk, bv,
                                    qbuf, kbuf, vbuf);

  attn_fwd<<<dim3(32, 16), 512, 0, stream>>>(qbuf, kbuf, vbuf, ids, abuf);

  gemm_out<<<512, 256, 0, stream>>>(abuf, wob, bo, out);
}